// Round 1
// baseline (94.115 us; speedup 1.0000x reference)
//
#include <hip/hip_runtime.h>

// Problem: B=32768 batch, I=16 in, O=16 heads, H=512 hidden, LeakyReLU(0.2)
// out[b,o] = sum_h W2[o,h]*leaky(sum_i x[b,i]*W1[o,h,i] + b1[o,h]) + b2[o]
//
// Identity: leaky(h) = h - 0.8*min(h,0)
//  => out[b,o] = (v[o]·x[b] + c[o]) - 0.8 * sum_h W2[o,h]*min(h[b,o,h],0)
//     v[o,i] = sum_h W2[o,h]*W1[o,h,i],  c[o] = sum_h W2[o,h]*b1[o,h] + b2[o]
// Linear part exact in fp32; nonlinear part via f16 MFMA (16x16x32, K padded:
// k=16 slot carries bias: A[.,16]=1, B[16,col]=b1).

#define B_DIM 32768
#define I_DIM 16
#define O_DIM 16
#define H_DIM 512

typedef _Float16 f16x8 __attribute__((ext_vector_type(8)));
typedef float    f32x4 __attribute__((ext_vector_type(4)));

// ws layout (bytes)
#define W1B_OFF   0          // 16 o * 32 ct * 32 lanes * 8 halves * 2B = 256 KiB
#define B1H_OFF   262144     // 8192 halves = 16 KiB
#define VMAT_OFF  278528     // 256 floats = 1 KiB
#define CVEC_OFF  279552     // 16 floats

// --- prep: W1 -> f16 B-fragment layout -------------------------------------
// For column tile (o, ct): lane l (<32), elem j: B[k=(l>>4)*8+j][col=l&15]
//   = W1[o][ct*16 + (l&15)][(l>>4)*8 + j]   (k in 0..15)
__global__ void prep_w1(const float* __restrict__ W1, ushort* __restrict__ w1B) {
    int t = blockIdx.x * 256 + threadIdx.x;      // 0..16383
    int o = t >> 10, rem = t & 1023, ct = rem >> 5, l = rem & 31;
    const float* src = W1 + ((o * H_DIM + ct * 16 + (l & 15)) * I_DIM + (l >> 4) * 8);
    f16x8 v;
#pragma unroll
    for (int j = 0; j < 8; ++j) v[j] = (_Float16)src[j];
    *reinterpret_cast<f16x8*>(w1B + ((size_t)(o * 32 + ct) * 32 + l) * 8) = v;
}

// --- prep: b1 -> f16, v[o,i], c[o] -----------------------------------------
__global__ void prep_small(const float* __restrict__ W1, const float* __restrict__ b1,
                           const float* __restrict__ W2, const float* __restrict__ b2,
                           ushort* __restrict__ b1h_u, float* __restrict__ vmat,
                           float* __restrict__ cvec) {
    int t = threadIdx.x;
    _Float16* b1h = reinterpret_cast<_Float16*>(b1h_u);
    for (int j = t; j < O_DIM * H_DIM; j += 256) b1h[j] = (_Float16)b1[j];
    int o = t >> 4, i = t & 15;
    float acc = 0.f;
    for (int h = 0; h < H_DIM; ++h)
        acc = fmaf(W2[o * H_DIM + h], W1[(o * H_DIM + h) * I_DIM + i], acc);
    vmat[t] = acc;
    if (i == 0) {
        float cacc = b2[o];
        for (int h = 0; h < H_DIM; ++h)
            cacc = fmaf(W2[o * H_DIM + h], b1[o * H_DIM + h], cacc);
        cvec[o] = cacc;
    }
}

// --- main ------------------------------------------------------------------
// block = 256 (4 waves). Each wave: 2 batch-tiles of 16 rows, one head o.
// grid = 256 groups * 16 o = 4096 blocks.
__global__ __launch_bounds__(256) void mlp_main(
    const float* __restrict__ x, const ushort* __restrict__ w1B_u,
    const ushort* __restrict__ b1h_u, const float* __restrict__ W2,
    const float* __restrict__ vmat, const float* __restrict__ cvec,
    float* __restrict__ out) {
    const int lane = threadIdx.x & 63;
    const int wid  = threadIdx.x >> 6;
    const int o    = blockIdx.x & 15;
    const int grp  = blockIdx.x >> 4;        // 0..255
    const int bt0  = grp * 8 + wid * 2;      // batch tile (16 rows each)
    const int col  = lane & 15;
    const int kg   = lane >> 4;              // 0..3

    // A fragments for the two batch tiles (k = kg*8+j; k>=16 pad, k==16 -> 1.0)
    f16x8 a0 = {}, a1 = {};
    if (kg < 2) {
        const float* p0 = x + ((size_t)(bt0 * 16 + col)) * I_DIM + kg * 8;
        const float* p1 = p0 + 16 * I_DIM;
#pragma unroll
        for (int j = 0; j < 8; ++j) { a0[j] = (_Float16)p0[j]; a1[j] = (_Float16)p1[j]; }
    } else if (kg == 2) {
        a0[0] = (_Float16)1.f; a1[0] = (_Float16)1.f;
    }

    const _Float16* b1h  = reinterpret_cast<const _Float16*>(b1h_u);
    const f16x8* bbase   = reinterpret_cast<const f16x8*>(w1B_u) + (size_t)o * 32 * 32;
    const float* w2p     = W2 + o * H_DIM + col;
    const _Float16* b1p  = b1h + o * H_DIM + col;

    f32x4 nl0 = {}, nl1 = {};
#pragma unroll 4
    for (int ct = 0; ct < 32; ++ct) {
        f16x8 bf = {};
        if (kg < 2)        bf    = bbase[ct * 32 + lane];
        else if (kg == 2)  bf[0] = b1p[ct * 16];       // k==16 slot: bias
        float w2v = w2p[ct * 16];
        f32x4 z = {};
        f32x4 d0 = __builtin_amdgcn_mfma_f32_16x16x32_f16(a0, bf, z, 0, 0, 0);
        f32x4 d1 = __builtin_amdgcn_mfma_f32_16x16x32_f16(a1, bf, z, 0, 0, 0);
#pragma unroll
        for (int r = 0; r < 4; ++r) {
            nl0[r] = fmaf(w2v, fminf(d0[r], 0.f), nl0[r]);
            nl1[r] = fmaf(w2v, fminf(d1[r], 0.f), nl1[r]);
        }
    }

    // reduce over the 16 columns (lanes sharing kg)
#pragma unroll
    for (int m = 1; m <= 8; m <<= 1) {
#pragma unroll
        for (int r = 0; r < 4; ++r) {
            nl0[r] += __shfl_xor(nl0[r], m, 64);
            nl1[r] += __shfl_xor(nl1[r], m, 64);
        }
    }

    if (col < 4) {
        const int r   = col;
        const int row = kg * 4 + r;          // D row = (lane>>4)*4 + reg
        float s0 = (r == 0) ? nl0[0] : (r == 1) ? nl0[1] : (r == 2) ? nl0[2] : nl0[3];
        float s1 = (r == 0) ? nl1[0] : (r == 1) ? nl1[1] : (r == 2) ? nl1[2] : nl1[3];
        const float* vp = vmat + o * 16;
        float cv = cvec[o];

        int b0 = bt0 * 16 + row;
        const float* xr0 = x + (size_t)b0 * I_DIM;
        float lin0 = cv;
#pragma unroll
        for (int i = 0; i < 16; ++i) lin0 = fmaf(vp[i], xr0[i], lin0);
        out[(size_t)b0 * O_DIM + o] = lin0 - 0.8f * s0;

        int b1i = (bt0 + 1) * 16 + row;
        const float* xr1 = x + (size_t)b1i * I_DIM;
        float lin1 = cv;
#pragma unroll
        for (int i = 0; i < 16; ++i) lin1 = fmaf(vp[i], xr1[i], lin1);
        out[(size_t)b1i * O_DIM + o] = lin1 - 0.8f * s1;
    }
}

extern "C" void kernel_launch(void* const* d_in, const int* in_sizes, int n_in,
                              void* d_out, int out_size, void* d_ws, size_t ws_size,
                              hipStream_t stream) {
    const float* x  = (const float*)d_in[0];
    const float* W1 = (const float*)d_in[1];
    const float* b1 = (const float*)d_in[2];
    const float* W2 = (const float*)d_in[3];
    const float* b2 = (const float*)d_in[4];
    float* out = (float*)d_out;
    char* ws = (char*)d_ws;

    ushort* w1B  = (ushort*)(ws + W1B_OFF);
    ushort* b1h  = (ushort*)(ws + B1H_OFF);
    float*  vmat = (float*)(ws + VMAT_OFF);
    float*  cvec = (float*)(ws + CVEC_OFF);

    prep_w1<<<64, 256, 0, stream>>>(W1, w1B);
    prep_small<<<1, 256, 0, stream>>>(W1, b1, W2, b2, b1h, vmat, cvec);
    mlp_main<<<4096, 256, 0, stream>>>(x, w1B, b1h, W2, vmat, cvec, out);
}

// Round 2
// 48.054 us; speedup vs baseline: 1.9585x; 1.9585x over previous
//
#include <hip/hip_runtime.h>

// out[b,o] = sum_h W2[o,h]*leaky(h[b,o,h]) + b2[o],  h = W1[o]·x[b] + b1[o]
// Identity: leaky(t) = t - 0.8*min(t,0)
//   out[b,o] = (v[o]·x[b] + c[o]) - 0.8 * sum_h W2[o,h]*min(h,0)
//   v[o,i] = sum_h W2[o,h]W1[o,h,i];  c[o] = sum_h W2[o,h]b1[o,h] + b2[o]
// Both parts via f16 MFMA 16x16x32 (K padded to 32; k=16 slot carries bias).
// This round: weights live in VGPRs (one head per wave), zero-load inner loop,
// linear part as a 33rd MFMA, parallel prep kernels.

#define B_DIM 32768
#define I_DIM 16
#define O_DIM 16
#define H_DIM 512

typedef _Float16 f16x8 __attribute__((ext_vector_type(8)));
typedef float    f32x4 __attribute__((ext_vector_type(4)));

// ws layout (bytes)
#define BFRAG_OFF 0            // [16 o][32 ct][64 lane][8 f16] = 512 KiB
#define BLIN_OFF  (512 * 1024) // [16 o][64 lane][8 f16] = 16 KiB

// --- prep: combined W1+bias B-fragments ------------------------------------
// bfrag[o][ct][lane][j]: kg=lane>>4, col=lane&15
//   kg<2 : W1[o][ct*16+col][kg*8+j]
//   kg==2: j==0 -> b1[o][ct*16+col], else 0
//   kg==3: 0
__global__ void prep_frag(const float* __restrict__ W1, const float* __restrict__ b1,
                          ushort* __restrict__ bfrag) {
    int t = blockIdx.x * 256 + threadIdx.x;   // 0..32767 = [o][ct][lane]
    int lane = t & 63, ct = (t >> 6) & 31, o = t >> 11;
    int col = lane & 15, kg = lane >> 4;
    f16x8 v = {};
    if (kg < 2) {
        const float* src = W1 + ((size_t)(o * H_DIM + ct * 16 + col) * I_DIM + kg * 8);
#pragma unroll
        for (int j = 0; j < 8; ++j) v[j] = (_Float16)src[j];
    } else if (kg == 2) {
        v[0] = (_Float16)b1[o * H_DIM + ct * 16 + col];
    }
    *reinterpret_cast<f16x8*>(bfrag + (size_t)t * 8) = v;
}

// --- prep: v, c -> blin fragment -------------------------------------------
__global__ void prep_vc(const float* __restrict__ W1, const float* __restrict__ b1,
                        const float* __restrict__ W2, const float* __restrict__ b2,
                        ushort* __restrict__ blin) {
    __shared__ float red[256];
    __shared__ float v_sm[16];
    __shared__ float c_sm;
    const int o = blockIdx.x, t = threadIdx.x;
    const int i = t & 15, hc = t >> 4;        // 16 chunks x 32 h
    float acc = 0.f;
    for (int hh = 0; hh < 32; ++hh) {
        int h = hc * 32 + hh;
        acc = fmaf(W2[o * H_DIM + h], W1[(size_t)(o * H_DIM + h) * I_DIM + i], acc);
    }
    red[t] = acc;
    __syncthreads();
    if (t < 16) {
        float s = 0.f;
        for (int k = 0; k < 16; ++k) s += red[t + 16 * k];
        v_sm[t] = s;
    }
    __syncthreads();
    float cacc = 0.f;
    for (int h = t; h < H_DIM; h += 256) cacc += W2[o * H_DIM + h] * b1[o * H_DIM + h];
    red[t] = cacc;
    __syncthreads();
    if (t == 0) {
        float s = b2[o];
        for (int k = 0; k < 256; ++k) s += red[k];
        c_sm = s;
    }
    __syncthreads();
    if (t < 64) {
        int kg = t >> 4;
        f16x8 v = {};
        if (kg < 2) {
#pragma unroll
            for (int j = 0; j < 8; ++j) v[j] = (_Float16)v_sm[kg * 8 + j];
        } else if (kg == 2) {
            v[0] = (_Float16)c_sm;
        }
        *reinterpret_cast<f16x8*>(blin + (size_t)(o * 64 + t) * 8) = v;
    }
}

// --- main ------------------------------------------------------------------
// 1024 blocks x 256 thr. o = blk&15, grp = blk>>4 (64 groups).
// Wave w handles pair-jobs p = grp*16 + w*4 + {0..3}; each job = 32 batch rows.
__global__ __launch_bounds__(256, 2) void mlp_main(
    const float* __restrict__ x, const ushort* __restrict__ bfrag_u,
    const ushort* __restrict__ blin_u, const float* __restrict__ W2,
    float* __restrict__ out) {
    const int lane = threadIdx.x & 63;
    const int w    = threadIdx.x >> 6;
    const int o    = blockIdx.x & 15;
    const int grp  = blockIdx.x >> 4;
    const int col  = lane & 15;
    const int kg   = lane >> 4;

    // --- load all weights into registers (once per wave) ---
    f16x8 bf[32];
    const f16x8* bp = reinterpret_cast<const f16x8*>(bfrag_u) + (size_t)o * 32 * 64 + lane;
#pragma unroll
    for (int ct = 0; ct < 32; ++ct) bf[ct] = bp[ct * 64];
    const f16x8 bl = reinterpret_cast<const f16x8*>(blin_u)[o * 64 + lane];
    float w2r[32];
#pragma unroll
    for (int ct = 0; ct < 32; ++ct) w2r[ct] = W2[o * H_DIM + ct * 16 + col];

    // constant parts of A fragments (k==16 -> 1.0 for bias slot)
    f16x8 a_const = {};
    if (kg == 2) a_const[0] = (_Float16)1.f;

    const f32x4 zero = {0.f, 0.f, 0.f, 0.f};

    for (int t = 0; t < 4; ++t) {
        const int p  = grp * 16 + w * 4 + t;   // pair index, 0..1023
        const int rb = p * 32;                 // 32 batch rows

        f16x8 a0 = a_const, a1 = a_const;
        if (kg < 2) {
            const float* p0 = x + (size_t)(rb + col) * I_DIM + kg * 8;
            const float* p1 = p0 + 16 * I_DIM;
#pragma unroll
            for (int j = 0; j < 8; ++j) { a0[j] = (_Float16)p0[j]; a1[j] = (_Float16)p1[j]; }
        }

        f32x4 nl0 = {}, nl1 = {};
#pragma unroll
        for (int ct = 0; ct < 32; ++ct) {
            f32x4 d0 = __builtin_amdgcn_mfma_f32_16x16x32_f16(a0, bf[ct], zero, 0, 0, 0);
            f32x4 d1 = __builtin_amdgcn_mfma_f32_16x16x32_f16(a1, bf[ct], zero, 0, 0, 0);
            const float w2v = w2r[ct];
#pragma unroll
            for (int r = 0; r < 4; ++r) {
                nl0[r] = fmaf(w2v, fminf(d0[r], 0.f), nl0[r]);
                nl1[r] = fmaf(w2v, fminf(d1[r], 0.f), nl1[r]);
            }
        }
        // linear part: one MFMA per tile
        f32x4 dl0 = __builtin_amdgcn_mfma_f32_16x16x32_f16(a0, bl, zero, 0, 0, 0);
        f32x4 dl1 = __builtin_amdgcn_mfma_f32_16x16x32_f16(a1, bl, zero, 0, 0, 0);

        // reduce nl over the 16 columns (lanes sharing kg)
#pragma unroll
        for (int m = 1; m <= 8; m <<= 1) {
#pragma unroll
            for (int r = 0; r < 4; ++r) {
                nl0[r] += __shfl_xor(nl0[r], m, 64);
                nl1[r] += __shfl_xor(nl1[r], m, 64);
            }
        }

        if (col < 4) {
            const int r   = col;
            const int row = kg * 4 + r;        // D row = (lane>>4)*4 + reg
            float s0 = (r == 0) ? nl0[0] : (r == 1) ? nl0[1] : (r == 2) ? nl0[2] : nl0[3];
            float s1 = (r == 0) ? nl1[0] : (r == 1) ? nl1[1] : (r == 2) ? nl1[2] : nl1[3];
            float l0 = (r == 0) ? dl0[0] : (r == 1) ? dl0[1] : (r == 2) ? dl0[2] : dl0[3];
            float l1 = (r == 0) ? dl1[0] : (r == 1) ? dl1[1] : (r == 2) ? dl1[2] : dl1[3];
            out[(size_t)(rb + row) * O_DIM + o]      = l0 - 0.8f * s0;
            out[(size_t)(rb + 16 + row) * O_DIM + o] = l1 - 0.8f * s1;
        }
    }
}

extern "C" void kernel_launch(void* const* d_in, const int* in_sizes, int n_in,
                              void* d_out, int out_size, void* d_ws, size_t ws_size,
                              hipStream_t stream) {
    const float* x  = (const float*)d_in[0];
    const float* W1 = (const float*)d_in[1];
    const float* b1 = (const float*)d_in[2];
    const float* W2 = (const float*)d_in[3];
    const float* b2 = (const float*)d_in[4];
    float* out = (float*)d_out;
    char* ws = (char*)d_ws;

    ushort* bfrag = (ushort*)(ws + BFRAG_OFF);
    ushort* blin  = (ushort*)(ws + BLIN_OFF);

    prep_frag<<<128, 256, 0, stream>>>(W1, b1, bfrag);
    prep_vc<<<16, 256, 0, stream>>>(W1, b1, W2, b2, blin);
    mlp_main<<<1024, 256, 0, stream>>>(x, bfrag, blin, W2, out);
}

// Round 3
// 45.599 us; speedup vs baseline: 2.0640x; 1.0539x over previous
//
#include <hip/hip_runtime.h>

// out[b,o] = sum_h W2[o,h]*leaky(h[b,o,h]) + b2[o],  h = W1[o]·x[b] + b1[o]
// leaky(t) = t - 0.8*min(t,0)
//   out[b,o] = (v[o]·x[b] + c[o]) - 0.8 * sum_h W2[o,h]*min(h,0)
// Stage-1 h via f16 MFMA 16x16x32 (K padded to 32, k=16 slot carries bias).
// Linear part via one extra MFMA (blin fragment holds v,c).
// This round: weights staged in LDS (35KB/block, 4 blocks/CU), x pre-converted
// to f16, 4 batch-tiles per wave (one ds_read feeds 4 MFMAs), 2048 blocks.

#define B_DIM 32768
#define I_DIM 16
#define O_DIM 16
#define H_DIM 512

typedef _Float16 f16x8 __attribute__((ext_vector_type(8)));
typedef float    f32x4 __attribute__((ext_vector_type(4)));

// ws layout (bytes)
#define BFRAG_OFF 0                 // [16 o][32 ct][64 lane][8 f16] = 512 KiB
#define BLIN_OFF  (512 * 1024)      // [16 o][64 lane][8 f16] = 16 KiB
#define XH_OFF    (528 * 1024)      // 32768*16 f16 = 1 MiB

// --- prep: W1+bias fragments, and x -> f16 ---------------------------------
__global__ void prep_fx(const float* __restrict__ W1, const float* __restrict__ b1,
                        const float* __restrict__ x,
                        ushort* __restrict__ bfrag, ushort* __restrict__ xh) {
    int blk = blockIdx.x;
    if (blk < 128) {
        int t = blk * 256 + threadIdx.x;      // [o][ct][lane]
        int lane = t & 63, ct = (t >> 6) & 31, o = t >> 11;
        int col = lane & 15, kg = lane >> 4;
        f16x8 v = {};
        if (kg < 2) {
            const float* src = W1 + ((size_t)(o * H_DIM + ct * 16 + col) * I_DIM + kg * 8);
#pragma unroll
            for (int j = 0; j < 8; ++j) v[j] = (_Float16)src[j];
        } else if (kg == 2) {
            v[0] = (_Float16)b1[o * H_DIM + ct * 16 + col];
        }
        *reinterpret_cast<f16x8*>(bfrag + (size_t)t * 8) = v;
    } else {
        int t = (blk - 128) * 256 + threadIdx.x;   // 0..65535, 8 f16 each
        const float* src = x + (size_t)t * 8;
        f16x8 v;
#pragma unroll
        for (int j = 0; j < 8; ++j) v[j] = (_Float16)src[j];
        *reinterpret_cast<f16x8*>(xh + (size_t)t * 8) = v;
    }
}

// --- prep: v, c -> blin fragment -------------------------------------------
__global__ void prep_vc(const float* __restrict__ W1, const float* __restrict__ b1,
                        const float* __restrict__ W2, const float* __restrict__ b2,
                        ushort* __restrict__ blin) {
    __shared__ float red[256];
    __shared__ float v_sm[16];
    __shared__ float c_sm;
    const int o = blockIdx.x, t = threadIdx.x;
    const int i = t & 15, hc = t >> 4;
    float acc = 0.f;
    for (int hh = 0; hh < 32; ++hh) {
        int h = hc * 32 + hh;
        acc = fmaf(W2[o * H_DIM + h], W1[(size_t)(o * H_DIM + h) * I_DIM + i], acc);
    }
    red[t] = acc;
    __syncthreads();
    if (t < 16) {
        float s = 0.f;
        for (int k = 0; k < 16; ++k) s += red[t + 16 * k];
        v_sm[t] = s;
    }
    __syncthreads();
    float cacc = 0.f;
    for (int h = t; h < H_DIM; h += 256) cacc += W2[o * H_DIM + h] * b1[o * H_DIM + h];
    red[t] = cacc;
    __syncthreads();
    if (t == 0) {
        float s = b2[o];
        for (int k = 0; k < 256; ++k) s += red[k];
        c_sm = s;
    }
    __syncthreads();
    if (t < 64) {
        int kg = t >> 4;
        f16x8 v = {};
        if (kg < 2) {
#pragma unroll
            for (int j = 0; j < 8; ++j) v[j] = (_Float16)v_sm[kg * 8 + j];
        } else if (kg == 2) {
            v[0] = (_Float16)c_sm;
        }
        *reinterpret_cast<f16x8*>(blin + (size_t)(o * 64 + t) * 8) = v;
    }
}

// --- main ------------------------------------------------------------------
// 2048 blocks x 256 thr (4 waves). o = blk&15 (also pins head to one XCD's L2),
// grp = blk>>4 (128). Wave w: 64 batch rows = 4 MFMA tiles, rb=(grp*4+w)*64.
__global__ __launch_bounds__(256, 4) void mlp_main(
    const ushort* __restrict__ xh_u, const ushort* __restrict__ bfrag_u,
    const ushort* __restrict__ blin_u, const float* __restrict__ W2,
    float* __restrict__ out) {
    __shared__ f16x8 sm_bf[2048];     // [ct][lane]  32 KiB
    __shared__ float sm_w2[512];      //  2 KiB
    __shared__ f16x8 sm_bl[64];       //  1 KiB

    const int tid = threadIdx.x;
    const int o   = blockIdx.x & 15;
    const int grp = blockIdx.x >> 4;

    const f16x8* gbf = reinterpret_cast<const f16x8*>(bfrag_u) + (size_t)o * 2048;
#pragma unroll
    for (int i = 0; i < 8; ++i) sm_bf[i * 256 + tid] = gbf[i * 256 + tid];
    sm_w2[tid]       = W2[o * H_DIM + tid];
    sm_w2[tid + 256] = W2[o * H_DIM + tid + 256];
    if (tid < 64) sm_bl[tid] = reinterpret_cast<const f16x8*>(blin_u)[o * 64 + tid];
    __syncthreads();

    const int lane = tid & 63, w = tid >> 6;
    const int col = lane & 15, kg = lane >> 4;
    const int rb = (grp * 4 + w) * 64;

    const _Float16* xh = reinterpret_cast<const _Float16*>(xh_u);
    f16x8 a[4];
    if (kg < 2) {
#pragma unroll
        for (int t = 0; t < 4; ++t)
            a[t] = *reinterpret_cast<const f16x8*>(xh + (size_t)(rb + t * 16 + col) * 16 + kg * 8);
    } else {
        f16x8 z = {};
        if (kg == 2) z[0] = (_Float16)1.f;
#pragma unroll
        for (int t = 0; t < 4; ++t) a[t] = z;
    }

    const f32x4 zero = {0.f, 0.f, 0.f, 0.f};
    f32x4 nl[4] = {zero, zero, zero, zero};

#pragma unroll 8
    for (int ct = 0; ct < 32; ++ct) {
        const f16x8 bfc = sm_bf[ct * 64 + lane];
        const float w2v = sm_w2[ct * 16 + col];
        f32x4 d0 = __builtin_amdgcn_mfma_f32_16x16x32_f16(a[0], bfc, zero, 0, 0, 0);
        f32x4 d1 = __builtin_amdgcn_mfma_f32_16x16x32_f16(a[1], bfc, zero, 0, 0, 0);
        f32x4 d2 = __builtin_amdgcn_mfma_f32_16x16x32_f16(a[2], bfc, zero, 0, 0, 0);
        f32x4 d3 = __builtin_amdgcn_mfma_f32_16x16x32_f16(a[3], bfc, zero, 0, 0, 0);
#pragma unroll
        for (int r = 0; r < 4; ++r) {
            nl[0][r] = fmaf(w2v, fminf(d0[r], 0.f), nl[0][r]);
            nl[1][r] = fmaf(w2v, fminf(d1[r], 0.f), nl[1][r]);
            nl[2][r] = fmaf(w2v, fminf(d2[r], 0.f), nl[2][r]);
            nl[3][r] = fmaf(w2v, fminf(d3[r], 0.f), nl[3][r]);
        }
    }

    // linear part: one MFMA per tile
    const f16x8 blf = sm_bl[lane];
    f32x4 dl[4];
#pragma unroll
    for (int t = 0; t < 4; ++t)
        dl[t] = __builtin_amdgcn_mfma_f32_16x16x32_f16(a[t], blf, zero, 0, 0, 0);

    // reduce nl over the 16 columns (lanes sharing kg)
#pragma unroll
    for (int m = 1; m <= 8; m <<= 1) {
#pragma unroll
        for (int t = 0; t < 4; ++t) {
#pragma unroll
            for (int r = 0; r < 4; ++r) nl[t][r] += __shfl_xor(nl[t][r], m, 64);
        }
    }

    if (col < 4) {
        const int r = col;
        const int row = kg * 4 + r;            // D row = (lane>>4)*4 + reg
#pragma unroll
        for (int t = 0; t < 4; ++t) {
            float s = (r == 0) ? nl[t][0] : (r == 1) ? nl[t][1] : (r == 2) ? nl[t][2] : nl[t][3];
            float l = (r == 0) ? dl[t][0] : (r == 1) ? dl[t][1] : (r == 2) ? dl[t][2] : dl[t][3];
            out[(size_t)(rb + t * 16 + row) * O_DIM + o] = l - 0.8f * s;
        }
    }
}

extern "C" void kernel_launch(void* const* d_in, const int* in_sizes, int n_in,
                              void* d_out, int out_size, void* d_ws, size_t ws_size,
                              hipStream_t stream) {
    const float* x  = (const float*)d_in[0];
    const float* W1 = (const float*)d_in[1];
    const float* b1 = (const float*)d_in[2];
    const float* W2 = (const float*)d_in[3];
    const float* b2 = (const float*)d_in[4];
    float* out = (float*)d_out;
    char* ws = (char*)d_ws;

    ushort* bfrag = (ushort*)(ws + BFRAG_OFF);
    ushort* blin  = (ushort*)(ws + BLIN_OFF);
    ushort* xh    = (ushort*)(ws + XH_OFF);

    prep_fx<<<384, 256, 0, stream>>>(W1, b1, x, bfrag, xh);
    prep_vc<<<16, 256, 0, stream>>>(W1, b1, W2, b2, blin);
    mlp_main<<<2048, 256, 0, stream>>>(xh, bfrag, blin, W2, out);
}

// Round 4
// 38.281 us; speedup vs baseline: 2.4585x; 1.1911x over previous
//
#include <hip/hip_runtime.h>

// out[b,o] = sum_h W2[o,h]*leaky(h[b,o,h]) + b2[o],  h = W1[o]·x[b] + b1[o]
// Identity: leaky(t) = 0.6t + 0.4|t|
//   out[b,o] = 0.6*(v[o]·x[b] + c0[o]) + b2[o] + sum_h (0.4*W2[o,h])*|h|
//   v[o,i] = sum_h W2[o,h]W1[o,h,i];  c0[o] = sum_h W2[o,h]b1[o,h]
// h via f16 MFMA 16x16x32 (K padded to 32, k=16 slot carries b1 so |h| has
// bias inside). |d| folds into the FMA operand modifier -> 1 VALU/elem.
// 8 batch-tiles per wave; weights in LDS; grid exactly 4 blocks/CU.

#define B_DIM 32768
#define I_DIM 16
#define O_DIM 16
#define H_DIM 512

typedef _Float16 f16x8 __attribute__((ext_vector_type(8)));
typedef float    f32x4 __attribute__((ext_vector_type(4)));

// ws layout (bytes)
#define BFRAG_OFF 0                 // [16 o][32 ct][64 lane][8 f16] = 512 KiB
#define BLIN_OFF  (512 * 1024)      // [16 o][64 lane][8 f16] = 16 KiB
#define XH_OFF    (528 * 1024)      // 32768*16 f16 = 1 MiB

// --- prep (one kernel, 400 blocks) -----------------------------------------
// blk [0,128)  : W1+bias -> B fragments
// blk [128,384): x -> f16
// blk [384,400): v,c -> blin fragment (scaled 0.6; w2-part scaled elsewhere)
__global__ void prep_all(const float* __restrict__ W1, const float* __restrict__ b1,
                         const float* __restrict__ W2, const float* __restrict__ b2,
                         const float* __restrict__ x,
                         ushort* __restrict__ bfrag, ushort* __restrict__ xh,
                         ushort* __restrict__ blin) {
    int blk = blockIdx.x;
    if (blk < 128) {
        int t = blk * 256 + threadIdx.x;      // [o][ct][lane]
        int lane = t & 63, ct = (t >> 6) & 31, o = t >> 11;
        int col = lane & 15, kg = lane >> 4;
        f16x8 v = {};
        if (kg < 2) {
            const float* src = W1 + ((size_t)(o * H_DIM + ct * 16 + col) * I_DIM + kg * 8);
#pragma unroll
            for (int j = 0; j < 8; ++j) v[j] = (_Float16)src[j];
        } else if (kg == 2) {
            v[0] = (_Float16)b1[o * H_DIM + ct * 16 + col];
        }
        *reinterpret_cast<f16x8*>(bfrag + (size_t)t * 8) = v;
    } else if (blk < 384) {
        int t = (blk - 128) * 256 + threadIdx.x;   // 8 f16 each
        const float* src = x + (size_t)t * 8;
        f16x8 v;
#pragma unroll
        for (int j = 0; j < 8; ++j) v[j] = (_Float16)src[j];
        *reinterpret_cast<f16x8*>(xh + (size_t)t * 8) = v;
    } else {
        __shared__ float red[256];
        __shared__ float v_sm[16];
        __shared__ float c_sm;
        const int o = blk - 384, t = threadIdx.x;
        const int i = t & 15, hc = t >> 4;
        float acc = 0.f;
        for (int hh = 0; hh < 32; ++hh) {
            int h = hc * 32 + hh;
            acc = fmaf(W2[o * H_DIM + h], W1[(size_t)(o * H_DIM + h) * I_DIM + i], acc);
        }
        red[t] = acc;
        __syncthreads();
        if (t < 16) {
            float s = 0.f;
            for (int k = 0; k < 16; ++k) s += red[t + 16 * k];
            v_sm[t] = 0.6f * s;               // pre-scale linear part
        }
        __syncthreads();
        float cacc = 0.f;
        for (int h = t; h < H_DIM; h += 256) cacc += W2[o * H_DIM + h] * b1[o * H_DIM + h];
        red[t] = cacc;
        __syncthreads();
        if (t == 0) {
            float s = 0.f;
            for (int k = 0; k < 256; ++k) s += red[k];
            c_sm = 0.6f * s + b2[o];
        }
        __syncthreads();
        if (t < 64) {
            int kg = t >> 4;
            f16x8 v = {};
            if (kg < 2) {
#pragma unroll
                for (int j = 0; j < 8; ++j) v[j] = (_Float16)v_sm[kg * 8 + j];
            } else if (kg == 2) {
                v[0] = (_Float16)c_sm;
            }
            *reinterpret_cast<f16x8*>(blin + (size_t)(o * 64 + t) * 8) = v;
        }
    }
}

// --- main ------------------------------------------------------------------
// 1024 blocks x 256 thr (4 waves) = exactly 4 blocks/CU, all co-resident.
// o = blk&15 (pins head's fragments to one XCD's L2), grp = blk>>4 (64).
// Wave w: 128 batch rows = 8 MFMA tiles, rb = (grp*4+w)*128.
__global__ __launch_bounds__(256, 4) void mlp_main(
    const ushort* __restrict__ xh_u, const ushort* __restrict__ bfrag_u,
    const ushort* __restrict__ blin_u, const float* __restrict__ W2,
    float* __restrict__ out) {
    __shared__ f16x8 sm_bf[2048];     // [ct][lane]  32 KiB
    __shared__ float sm_w2[512];      //  2 KiB (pre-scaled by 0.4)
    __shared__ f16x8 sm_bl[64];       //  1 KiB

    const int tid = threadIdx.x;
    const int o   = blockIdx.x & 15;
    const int grp = blockIdx.x >> 4;

    const f16x8* gbf = reinterpret_cast<const f16x8*>(bfrag_u) + (size_t)o * 2048;
#pragma unroll
    for (int i = 0; i < 8; ++i) sm_bf[i * 256 + tid] = gbf[i * 256 + tid];
    sm_w2[tid]       = 0.4f * W2[o * H_DIM + tid];
    sm_w2[tid + 256] = 0.4f * W2[o * H_DIM + tid + 256];
    if (tid < 64) sm_bl[tid] = reinterpret_cast<const f16x8*>(blin_u)[o * 64 + tid];
    __syncthreads();

    const int lane = tid & 63, w = tid >> 6;
    const int col = lane & 15, kg = lane >> 4;
    const int rb = (grp * 4 + w) * 128;

    const _Float16* xh = reinterpret_cast<const _Float16*>(xh_u);
    f16x8 a[8];
    if (kg < 2) {
#pragma unroll
        for (int t = 0; t < 8; ++t)
            a[t] = *reinterpret_cast<const f16x8*>(xh + (size_t)(rb + t * 16 + col) * 16 + kg * 8);
    } else {
        f16x8 z = {};
        if (kg == 2) z[0] = (_Float16)1.f;
#pragma unroll
        for (int t = 0; t < 8; ++t) a[t] = z;
    }

    const f32x4 zero = {0.f, 0.f, 0.f, 0.f};
    f32x4 nl[8] = {zero, zero, zero, zero, zero, zero, zero, zero};

#pragma unroll 4
    for (int ct = 0; ct < 32; ++ct) {
        const f16x8 bfc = sm_bf[ct * 64 + lane];
        const float w2v = sm_w2[ct * 16 + col];
#pragma unroll
        for (int t = 0; t < 8; ++t) {
            f32x4 d = __builtin_amdgcn_mfma_f32_16x16x32_f16(a[t], bfc, zero, 0, 0, 0);
#pragma unroll
            for (int r = 0; r < 4; ++r)
                nl[t][r] = fmaf(w2v, fabsf(d[r]), nl[t][r]);   // abs = free modifier
        }
    }

    // linear part: one MFMA per tile (all 16 D-columns identical by design)
    const f16x8 blf = sm_bl[lane];
    f32x4 dl[8];
#pragma unroll
    for (int t = 0; t < 8; ++t)
        dl[t] = __builtin_amdgcn_mfma_f32_16x16x32_f16(a[t], blf, zero, 0, 0, 0);

    // reduce nl over the 16 columns (lanes sharing kg)
#pragma unroll
    for (int m = 1; m <= 8; m <<= 1) {
#pragma unroll
        for (int t = 0; t < 8; ++t) {
#pragma unroll
            for (int r = 0; r < 4; ++r) nl[t][r] += __shfl_xor(nl[t][r], m, 64);
        }
    }

    if (col < 4) {
        const int r = col;
        const int row = kg * 4 + r;            // D row = (lane>>4)*4 + reg
#pragma unroll
        for (int t = 0; t < 8; ++t) {
            float s = (r == 0) ? nl[t][0] : (r == 1) ? nl[t][1] : (r == 2) ? nl[t][2] : nl[t][3];
            float l = (r == 0) ? dl[t][0] : (r == 1) ? dl[t][1] : (r == 2) ? dl[t][2] : dl[t][3];
            out[(size_t)(rb + t * 16 + row) * O_DIM + o] = l + s;
        }
    }
}

extern "C" void kernel_launch(void* const* d_in, const int* in_sizes, int n_in,
                              void* d_out, int out_size, void* d_ws, size_t ws_size,
                              hipStream_t stream) {
    const float* x  = (const float*)d_in[0];
    const float* W1 = (const float*)d_in[1];
    const float* b1 = (const float*)d_in[2];
    const float* W2 = (const float*)d_in[3];
    const float* b2 = (const float*)d_in[4];
    float* out = (float*)d_out;
    char* ws = (char*)d_ws;

    ushort* bfrag = (ushort*)(ws + BFRAG_OFF);
    ushort* blin  = (ushort*)(ws + BLIN_OFF);
    ushort* xh    = (ushort*)(ws + XH_OFF);

    prep_all<<<400, 256, 0, stream>>>(W1, b1, W2, b2, x, bfrag, xh, blin);
    mlp_main<<<1024, 256, 0, stream>>>(xh, bfrag, blin, W2, out);
}

// Round 6
// 31.802 us; speedup vs baseline: 2.9594x; 1.2037x over previous
//
#include <hip/hip_runtime.h>

// out[b,o] = sum_h W2[o,h]*leaky(h) + b2[o],  h = W1[o]·x[b] + b1[o]
// leaky(t) = 0.6t + 0.4|t|
//   out[b,o] = 0.6(v[o]·x[b] + c0[o]) + b2[o] + sum_h (0.4 W2[o,h])|h|
// ALL matmul work on the MFMA pipe (16x16x32 f16, layouts verified R1-R4):
//   stage1 (swapped): D' = mfma(A=W1frag(bias in k=16), B=xfrag(1 in k=16))
//     -> lane holds 4 h-rows for its own b-col: exactly MFMA-A layout.
//   stage2: acc = mfma(A=pack(|D'_even|,|D'_odd|), B=0.4*W2 bcast-frag, acc)
//     B2 k->h permutation matches in-lane reg order; no cross-lane moves.
//   acc init = linear part: mfma(A=xfrag, B=[0.6v | 0.6c0+b2] bcast, 0).
// No shuffle reduce, no scalar-w2 fmaf chains. 8 b-tiles/wave for ILP.

#define B_DIM 32768
#define I_DIM 16
#define O_DIM 16
#define H_DIM 512

typedef _Float16 f16x8 __attribute__((ext_vector_type(8)));
typedef __fp16   h16x2 __attribute__((ext_vector_type(2)));   // cvt_pkrtz native
typedef float    f32x4 __attribute__((ext_vector_type(4)));

// ws layout (bytes)
#define BFRAG_OFF 0                  // [16 o][32 ct][64 lane][8 f16] = 512 KiB
#define BLIN_OFF  (512 * 1024)       // [16 o][64 lane][8 f16] = 16 KiB
#define W2F_OFF   (528 * 1024)       // [16 o][16 pair][64 lane][8 f16] = 256 KiB
#define XH_OFF    (784 * 1024)       // 32768*16 f16 = 1 MiB

// --- prep: everything ------------------------------------------------------
__global__ void prep_all(const float* __restrict__ W1, const float* __restrict__ b1,
                         const float* __restrict__ W2, const float* __restrict__ b2,
                         const float* __restrict__ x,
                         ushort* __restrict__ bfrag, ushort* __restrict__ xh,
                         ushort* __restrict__ blin, ushort* __restrict__ w2f) {
    int blk = blockIdx.x;
    if (blk < 128) {
        // W1+bias fragments: frag[o][ct][lane]: row(h)=lane&15, k=(lane>>4)*8+j
        int t = blk * 256 + threadIdx.x;
        int lane = t & 63, ct = (t >> 6) & 31, o = t >> 11;
        int row = lane & 15, kg = lane >> 4;
        f16x8 v = {};
        if (kg < 2) {
            const float* src = W1 + ((size_t)(o * H_DIM + ct * 16 + row) * I_DIM + kg * 8);
#pragma unroll
            for (int j = 0; j < 8; ++j) v[j] = (_Float16)src[j];
        } else if (kg == 2) {
            v[0] = (_Float16)b1[o * H_DIM + ct * 16 + row];
        }
        *reinterpret_cast<f16x8*>(bfrag + (size_t)t * 8) = v;
    } else if (blk < 384) {
        int t = (blk - 128) * 256 + threadIdx.x;
        const float* src = x + (size_t)t * 8;
        f16x8 v;
#pragma unroll
        for (int j = 0; j < 8; ++j) v[j] = (_Float16)src[j];
        *reinterpret_cast<f16x8*>(xh + (size_t)t * 8) = v;
    } else if (blk < 400) {
        // v[o,i], c -> blin broadcast fragment (0.6-scaled, +b2)
        __shared__ float red[256];
        __shared__ float v_sm[16];
        __shared__ float c_sm;
        const int o = blk - 384, t = threadIdx.x;
        const int i = t & 15, hc = t >> 4;
        float acc = 0.f;
        for (int hh = 0; hh < 32; ++hh) {
            int h = hc * 32 + hh;
            acc = fmaf(W2[o * H_DIM + h], W1[(size_t)(o * H_DIM + h) * I_DIM + i], acc);
        }
        red[t] = acc;
        __syncthreads();
        if (t < 16) {
            float s = 0.f;
            for (int k = 0; k < 16; ++k) s += red[t + 16 * k];
            v_sm[t] = 0.6f * s;
        }
        __syncthreads();
        float cacc = 0.f;
        for (int h = t; h < H_DIM; h += 256) cacc += W2[o * H_DIM + h] * b1[o * H_DIM + h];
        red[t] = cacc;
        __syncthreads();
        if (t == 0) {
            float s = 0.f;
            for (int k = 0; k < 256; ++k) s += red[k];
            c_sm = 0.6f * s + b2[o];
        }
        __syncthreads();
        if (t < 64) {
            int kg = t >> 4;
            f16x8 v = {};
            if (kg < 2) {
#pragma unroll
                for (int j = 0; j < 8; ++j) v[j] = (_Float16)v_sm[kg * 8 + j];
            } else if (kg == 2) {
                v[0] = (_Float16)c_sm;
            }
            *reinterpret_cast<f16x8*>(blin + (size_t)(o * 64 + t) * 8) = v;
        }
    } else {
        // 0.4*W2 broadcast fragments: w2f[o][pair][lane][j],
        // k=kg*8+j -> h = pair*32 + ((j>>2)&1)*16 + kg*4 + (j&3)
        int t = (blk - 400) * 256 + threadIdx.x;      // 0..16383
        int l = t & 63, pair = (t >> 6) & 15, o = t >> 10;
        int kg = l >> 4;
        f16x8 v;
#pragma unroll
        for (int j = 0; j < 8; ++j) {
            int h = pair * 32 + ((j >> 2) & 1) * 16 + kg * 4 + (j & 3);
            v[j] = (_Float16)(0.4f * W2[o * H_DIM + h]);
        }
        *reinterpret_cast<f16x8*>(w2f + (size_t)t * 8) = v;
    }
}

// --- main ------------------------------------------------------------------
// 512 blocks x 512 thr (8 waves), 2 blocks/CU (48KB LDS), 4 waves/SIMD.
// o = blk&15, grp = blk>>4 (32). Wave w: 128 batch rows, rb=(grp*8+w)*128.
__global__ __launch_bounds__(512, 4) void mlp_main(
    const ushort* __restrict__ xh_u, const ushort* __restrict__ bfrag_u,
    const ushort* __restrict__ blin_u, const ushort* __restrict__ w2f_u,
    float* __restrict__ out) {
    __shared__ f16x8 sm_a1[2048];     // [ct][lane]   32 KiB (W1+bias frags)
    __shared__ f16x8 sm_w2[1024];     // [pair][lane] 16 KiB (0.4*W2 frags)

    const int tid = threadIdx.x;
    const int o   = blockIdx.x & 15;
    const int grp = blockIdx.x >> 4;

    const f16x8* ga = reinterpret_cast<const f16x8*>(bfrag_u) + (size_t)o * 2048;
#pragma unroll
    for (int i = 0; i < 4; ++i) sm_a1[i * 512 + tid] = ga[i * 512 + tid];
    const f16x8* gw = reinterpret_cast<const f16x8*>(w2f_u) + (size_t)o * 1024;
#pragma unroll
    for (int i = 0; i < 2; ++i) sm_w2[i * 512 + tid] = gw[i * 512 + tid];
    __syncthreads();

    const int lane = tid & 63, w = tid >> 6;
    const int col = lane & 15, kg = lane >> 4;
    const int rb = (grp * 8 + w) * 128;

    // x fragments (role: B for stage1, A for linear init). k=16 slot = 1.
    const _Float16* xh = reinterpret_cast<const _Float16*>(xh_u);
    f16x8 xf[8];
    if (kg < 2) {
#pragma unroll
        for (int t = 0; t < 8; ++t)
            xf[t] = *reinterpret_cast<const f16x8*>(xh + (size_t)(rb + t * 16 + col) * 16 + kg * 8);
    } else {
        f16x8 z = {};
        if (kg == 2) z[0] = (_Float16)1.f;
#pragma unroll
        for (int t = 0; t < 8; ++t) xf[t] = z;
    }

    const f32x4 zero = {0.f, 0.f, 0.f, 0.f};
    // acc init = linear part: rows of D = rows of A = b
    const f16x8 blf = reinterpret_cast<const f16x8*>(blin_u)[o * 64 + lane];
    f32x4 acc[8];
#pragma unroll
    for (int t = 0; t < 8; ++t)
        acc[t] = __builtin_amdgcn_mfma_f32_16x16x32_f16(xf[t], blf, zero, 0, 0, 0);

    for (int p = 0; p < 16; ++p) {
        const f16x8 A1a = sm_a1[(2 * p) * 64 + lane];
        const f16x8 A1b = sm_a1[(2 * p + 1) * 64 + lane];
        const f16x8 B2  = sm_w2[p * 64 + lane];
#pragma unroll
        for (int t = 0; t < 8; ++t) {
            // stage1 swapped: D'[h][b]; lane holds 4 h for b=col
            f32x4 d0 = __builtin_amdgcn_mfma_f32_16x16x32_f16(A1a, xf[t], zero, 0, 0, 0);
            f32x4 d1 = __builtin_amdgcn_mfma_f32_16x16x32_f16(A1b, xf[t], zero, 0, 0, 0);
            // pack |d| -> A2 (k order matches w2f's k->h permutation)
            h16x2 p0 = __builtin_amdgcn_cvt_pkrtz(fabsf(d0[0]), fabsf(d0[1]));
            h16x2 p1 = __builtin_amdgcn_cvt_pkrtz(fabsf(d0[2]), fabsf(d0[3]));
            h16x2 p2 = __builtin_amdgcn_cvt_pkrtz(fabsf(d1[0]), fabsf(d1[1]));
            h16x2 p3 = __builtin_amdgcn_cvt_pkrtz(fabsf(d1[2]), fabsf(d1[3]));
            f16x8 A2;
            A2[0] = (_Float16)p0[0]; A2[1] = (_Float16)p0[1];
            A2[2] = (_Float16)p1[0]; A2[3] = (_Float16)p1[1];
            A2[4] = (_Float16)p2[0]; A2[5] = (_Float16)p2[1];
            A2[6] = (_Float16)p3[0]; A2[7] = (_Float16)p3[1];
            // stage2: accumulate 0.4*sum w2|h| on the MFMA pipe
            acc[t] = __builtin_amdgcn_mfma_f32_16x16x32_f16(A2, B2, acc[t], 0, 0, 0);
        }
    }

    // acc[t] reg r = out[rb + t*16 + kg*4 + r], identical across cols.
    if (col < 4) {
#pragma unroll
        for (int t = 0; t < 8; ++t) {
            float v = (col == 0) ? acc[t][0] : (col == 1) ? acc[t][1]
                    : (col == 2) ? acc[t][2] : acc[t][3];
            out[(size_t)(rb + t * 16 + kg * 4 + col) * O_DIM + o] = v;
        }
    }
}

extern "C" void kernel_launch(void* const* d_in, const int* in_sizes, int n_in,
                              void* d_out, int out_size, void* d_ws, size_t ws_size,
                              hipStream_t stream) {
    const float* x  = (const float*)d_in[0];
    const float* W1 = (const float*)d_in[1];
    const float* b1 = (const float*)d_in[2];
    const float* W2 = (const float*)d_in[3];
    const float* b2 = (const float*)d_in[4];
    float* out = (float*)d_out;
    char* ws = (char*)d_ws;

    ushort* bfrag = (ushort*)(ws + BFRAG_OFF);
    ushort* blin  = (ushort*)(ws + BLIN_OFF);
    ushort* w2f   = (ushort*)(ws + W2F_OFF);
    ushort* xh    = (ushort*)(ws + XH_OFF);

    prep_all<<<464, 256, 0, stream>>>(W1, b1, W2, b2, x, bfrag, xh, blin, w2f);
    mlp_main<<<512, 512, 0, stream>>>(xh, bfrag, blin, w2f, out);
}

// Round 7
// 30.351 us; speedup vs baseline: 3.1009x; 1.0478x over previous
//
#include <hip/hip_runtime.h>

// out[b,o] = sum_h W2[o,h]*leaky(h) + b2[o],  h = W1[o]·x[b] + b1[o]
// leaky(t) = 0.6t + 0.4|t|
//   out[b,o] = 0.6(v[o]·x[b] + c0[o]) + b2[o] + sum_h (0.4 W2[o,h])|h|
// ALL matmul on the MFMA pipe (16x16x32 f16):
//   stage1 (swapped): D' = mfma(A=W1frag(bias in k=16), B=xfrag(1 in k=16))
//   stage2: acc = mfma(A=pack(|D'|), B=0.4*W2 bcast-frag, acc)
//   acc init = linear part: mfma(A=xfrag, B=[0.6v | 0.6c0+b2] bcast, 0)
// R7: 4 tiles/wave (was 8) + unroll-2 p-loop to kill register spills.

#define B_DIM 32768
#define I_DIM 16
#define O_DIM 16
#define H_DIM 512

typedef _Float16 f16x8 __attribute__((ext_vector_type(8)));
typedef __fp16   h16x2 __attribute__((ext_vector_type(2)));   // cvt_pkrtz native
typedef float    f32x4 __attribute__((ext_vector_type(4)));
typedef int      i32x4 __attribute__((ext_vector_type(4)));

// ws layout (bytes)
#define BFRAG_OFF 0                  // [16 o][32 ct][64 lane][8 f16] = 512 KiB
#define BLIN_OFF  (512 * 1024)       // [16 o][64 lane][8 f16] = 16 KiB
#define W2F_OFF   (528 * 1024)       // [16 o][16 pair][64 lane][8 f16] = 256 KiB
#define XH_OFF    (784 * 1024)       // 32768*16 f16 = 1 MiB

// --- prep: everything ------------------------------------------------------
__global__ void prep_all(const float* __restrict__ W1, const float* __restrict__ b1,
                         const float* __restrict__ W2, const float* __restrict__ b2,
                         const float* __restrict__ x,
                         ushort* __restrict__ bfrag, ushort* __restrict__ xh,
                         ushort* __restrict__ blin, ushort* __restrict__ w2f) {
    int blk = blockIdx.x;
    if (blk < 128) {
        // W1+bias fragments: frag[o][ct][lane]: row(h)=lane&15, k=(lane>>4)*8+j
        int t = blk * 256 + threadIdx.x;
        int lane = t & 63, ct = (t >> 6) & 31, o = t >> 11;
        int row = lane & 15, kg = lane >> 4;
        f16x8 v = {};
        if (kg < 2) {
            const float* src = W1 + ((size_t)(o * H_DIM + ct * 16 + row) * I_DIM + kg * 8);
#pragma unroll
            for (int j = 0; j < 8; ++j) v[j] = (_Float16)src[j];
        } else if (kg == 2) {
            v[0] = (_Float16)b1[o * H_DIM + ct * 16 + row];
        }
        *reinterpret_cast<f16x8*>(bfrag + (size_t)t * 8) = v;
    } else if (blk < 384) {
        int t = (blk - 128) * 256 + threadIdx.x;
        const float* src = x + (size_t)t * 8;
        f16x8 v;
#pragma unroll
        for (int j = 0; j < 8; ++j) v[j] = (_Float16)src[j];
        *reinterpret_cast<f16x8*>(xh + (size_t)t * 8) = v;
    } else if (blk < 400) {
        // v[o,i], c -> blin broadcast fragment (0.6-scaled, +b2)
        __shared__ float red[256];
        __shared__ float v_sm[16];
        __shared__ float c_sm;
        const int o = blk - 384, t = threadIdx.x;
        const int i = t & 15, hc = t >> 4;
        float acc = 0.f;
        for (int hh = 0; hh < 32; ++hh) {
            int h = hc * 32 + hh;
            acc = fmaf(W2[o * H_DIM + h], W1[(size_t)(o * H_DIM + h) * I_DIM + i], acc);
        }
        red[t] = acc;
        __syncthreads();
        if (t < 16) {
            float s = 0.f;
#pragma unroll
            for (int k = 0; k < 16; ++k) s += red[t + 16 * k];
            v_sm[t] = 0.6f * s;
        }
        float cacc = 0.f;
        for (int h = t; h < H_DIM; h += 256) cacc += W2[o * H_DIM + h] * b1[o * H_DIM + h];
        __syncthreads();
        red[t] = cacc;
        __syncthreads();
        if (t < 64) {
            float s = red[t] + red[t + 64] + red[t + 128] + red[t + 192];
#pragma unroll
            for (int m = 1; m <= 32; m <<= 1) s += __shfl_xor(s, m, 64);
            if (t == 0) c_sm = 0.6f * s + b2[o];
        }
        __syncthreads();
        if (t < 64) {
            int kg = t >> 4;
            f16x8 v = {};
            if (kg < 2) {
#pragma unroll
                for (int j = 0; j < 8; ++j) v[j] = (_Float16)v_sm[kg * 8 + j];
            } else if (kg == 2) {
                v[0] = (_Float16)c_sm;
            }
            *reinterpret_cast<f16x8*>(blin + (size_t)(o * 64 + t) * 8) = v;
        }
    } else {
        // 0.4*W2 broadcast fragments: w2f[o][pair][lane][j],
        // k=kg*8+j -> h = pair*32 + ((j>>2)&1)*16 + kg*4 + (j&3)
        int t = (blk - 400) * 256 + threadIdx.x;      // 0..16383
        int l = t & 63, pair = (t >> 6) & 15, o = t >> 10;
        int kg = l >> 4;
        f16x8 v;
#pragma unroll
        for (int j = 0; j < 8; ++j) {
            int h = pair * 32 + ((j >> 2) & 1) * 16 + kg * 4 + (j & 3);
            v[j] = (_Float16)(0.4f * W2[o * H_DIM + h]);
        }
        *reinterpret_cast<f16x8*>(w2f + (size_t)t * 8) = v;
    }
}

// --- main ------------------------------------------------------------------
// 1024 blocks x 512 thr (8 waves). o = blk&15, grp = blk>>4 (64).
// Wave w: 64 batch rows = 4 MFMA tiles, rb = (grp*8+w)*64.
__global__ __launch_bounds__(512, 4) void mlp_main(
    const ushort* __restrict__ xh_u, const ushort* __restrict__ bfrag_u,
    const ushort* __restrict__ blin_u, const ushort* __restrict__ w2f_u,
    float* __restrict__ out) {
    __shared__ f16x8 sm_a1[2048];     // [ct][lane]   32 KiB (W1+bias frags)
    __shared__ f16x8 sm_w2[1024];     // [pair][lane] 16 KiB (0.4*W2 frags)

    const int tid = threadIdx.x;
    const int o   = blockIdx.x & 15;
    const int grp = blockIdx.x >> 4;

    const f16x8* ga = reinterpret_cast<const f16x8*>(bfrag_u) + (size_t)o * 2048;
#pragma unroll
    for (int i = 0; i < 4; ++i) sm_a1[i * 512 + tid] = ga[i * 512 + tid];
    const f16x8* gw = reinterpret_cast<const f16x8*>(w2f_u) + (size_t)o * 1024;
#pragma unroll
    for (int i = 0; i < 2; ++i) sm_w2[i * 512 + tid] = gw[i * 512 + tid];
    __syncthreads();

    const int lane = tid & 63, w = tid >> 6;
    const int col = lane & 15, kg = lane >> 4;
    const int rb = (grp * 8 + w) * 64;

    // x fragments (role: B for stage1, A for linear init). k=16 slot = 1.
    const _Float16* xh = reinterpret_cast<const _Float16*>(xh_u);
    f16x8 xf[4];
    if (kg < 2) {
#pragma unroll
        for (int t = 0; t < 4; ++t)
            xf[t] = *reinterpret_cast<const f16x8*>(xh + (size_t)(rb + t * 16 + col) * 16 + kg * 8);
    } else {
        f16x8 z = {};
        if (kg == 2) z[0] = (_Float16)1.f;
#pragma unroll
        for (int t = 0; t < 4; ++t) xf[t] = z;
    }

    const f32x4 zero = {0.f, 0.f, 0.f, 0.f};
    // acc init = linear part: rows of D = rows of A = b
    const f16x8 blf = reinterpret_cast<const f16x8*>(blin_u)[o * 64 + lane];
    f32x4 acc[4];
#pragma unroll
    for (int t = 0; t < 4; ++t)
        acc[t] = __builtin_amdgcn_mfma_f32_16x16x32_f16(xf[t], blf, zero, 0, 0, 0);

#pragma unroll 2
    for (int p = 0; p < 16; ++p) {
        const f16x8 A1a = sm_a1[(2 * p) * 64 + lane];
        const f16x8 A1b = sm_a1[(2 * p + 1) * 64 + lane];
        const f16x8 B2  = sm_w2[p * 64 + lane];
#pragma unroll
        for (int t = 0; t < 4; ++t) {
            // stage1 swapped: D'[h][b]; lane holds 4 h for b=col
            f32x4 d0 = __builtin_amdgcn_mfma_f32_16x16x32_f16(A1a, xf[t], zero, 0, 0, 0);
            f32x4 d1 = __builtin_amdgcn_mfma_f32_16x16x32_f16(A1b, xf[t], zero, 0, 0, 0);
            // pack |d| -> A2 (k order matches w2f's k->h permutation)
            h16x2 p0 = __builtin_amdgcn_cvt_pkrtz(fabsf(d0[0]), fabsf(d0[1]));
            h16x2 p1 = __builtin_amdgcn_cvt_pkrtz(fabsf(d0[2]), fabsf(d0[3]));
            h16x2 p2 = __builtin_amdgcn_cvt_pkrtz(fabsf(d1[0]), fabsf(d1[1]));
            h16x2 p3 = __builtin_amdgcn_cvt_pkrtz(fabsf(d1[2]), fabsf(d1[3]));
            i32x4 a2i;
            a2i[0] = __builtin_bit_cast(int, p0);
            a2i[1] = __builtin_bit_cast(int, p1);
            a2i[2] = __builtin_bit_cast(int, p2);
            a2i[3] = __builtin_bit_cast(int, p3);
            f16x8 A2 = __builtin_bit_cast(f16x8, a2i);
            // stage2: accumulate 0.4*sum w2|h| on the MFMA pipe
            acc[t] = __builtin_amdgcn_mfma_f32_16x16x32_f16(A2, B2, acc[t], 0, 0, 0);
        }
    }

    // acc[t] reg r = out[rb + t*16 + kg*4 + r], identical across cols.
    if (col < 4) {
#pragma unroll
        for (int t = 0; t < 4; ++t) {
            float v = (col == 0) ? acc[t][0] : (col == 1) ? acc[t][1]
                    : (col == 2) ? acc[t][2] : acc[t][3];
            out[(size_t)(rb + t * 16 + kg * 4 + col) * O_DIM + o] = v;
        }
    }
}

extern "C" void kernel_launch(void* const* d_in, const int* in_sizes, int n_in,
                              void* d_out, int out_size, void* d_ws, size_t ws_size,
                              hipStream_t stream) {
    const float* x  = (const float*)d_in[0];
    const float* W1 = (const float*)d_in[1];
    const float* b1 = (const float*)d_in[2];
    const float* W2 = (const float*)d_in[3];
    const float* b2 = (const float*)d_in[4];
    float* out = (float*)d_out;
    char* ws = (char*)d_ws;

    ushort* bfrag = (ushort*)(ws + BFRAG_OFF);
    ushort* blin  = (ushort*)(ws + BLIN_OFF);
    ushort* w2f   = (ushort*)(ws + W2F_OFF);
    ushort* xh    = (ushort*)(ws + XH_OFF);

    prep_all<<<464, 256, 0, stream>>>(W1, b1, W2, b2, x, bfrag, xh, blin, w2f);
    mlp_main<<<1024, 512, 0, stream>>>(xh, bfrag, blin, w2f, out);
}